// Round 9
// baseline (132.495 us; speedup 1.0000x reference)
//
#include <hip/hip_runtime.h>

#define RADIUS 5
#define WIN 9
#define BB 4
#define KK 4
#define HH 224
#define WW 224
#define HW (HH * WW)
#define PD 234                 // HH + 2*RADIUS
#define PAREA (PD * PD)        // 54756
#define NBUCKET 64
#define PARTIAL_FLOATS (NBUCKET * BB * 8)   // 2048 floats = 8 KB
#define ZERO_FLOATS 2064                    // partials + counter (+ pad)
#define BLOCKS_PER_B (HW / 64)              // 784
#define TOTAL_BLOCKS (BB * BLOCKS_PER_B)    // 3136

// d_ws layout (floats):
//   [0, 2048)                      : partial buckets [bucket][b][8] (0..3 A_k, 4..7 V_k)
//   [2048]                         : block-completion counter (unsigned)
//   [2560, 2560 + B*PAREA*4)       : padded seg P[b][r][c][k], float4 per (r,c)

// ---------- pre-pass: zero partials+counter, seg [B,K,H,W] -> zero-padded [B,PD,PD,K] ----------
__global__ __launch_bounds__(256) void ncuts_pad(
    const float* __restrict__ seg, float4* __restrict__ pseg, float* __restrict__ zr)
{
    const int tid = blockIdx.x * 256 + threadIdx.x;
    if (tid < ZERO_FLOATS) zr[tid] = 0.f;           // partial buckets + counter
    if (tid >= BB * PAREA) return;
    const int b  = tid / PAREA;
    const int rc = tid - b * PAREA;
    const int r  = rc / PD;
    const int c  = rc - r * PD;
    const int hh = r - RADIUS;
    const int ww = c - RADIUS;
    float4 v = {0.f, 0.f, 0.f, 0.f};
    if (hh >= 0 && hh < HH && ww >= 0 && ww < WW) {
        const float* sb = seg + (size_t)b * KK * HW + hh * WW + ww;
        v.x = sb[0 * HW];
        v.y = sb[1 * HW];
        v.z = sb[2 * HW];
        v.w = sb[3 * HW];
    }
    pseg[tid] = v;
}

// ---------- main: one wave = 64 pixels; rolling 2-row load buffer; fused fence-free final ----------
__global__ __launch_bounds__(64, 1) void ncuts_main(
    const float* __restrict__ weight,
    const float4* __restrict__ pseg,
    float* __restrict__ partial,
    unsigned* __restrict__ counter,
    float* __restrict__ out)
{
    __shared__ float wlds[64 * 81];   // 20736 B -> 7 blocks/CU (the occupancy cap)

    const int lane = threadIdx.x;     // 0..63
    const int tid  = blockIdx.x * 64 + lane;   // pixel id
    const int b    = tid / HW;        // uniform per block (784 blocks per b)
    const int rem  = tid - b * HW;
    const int h    = rem / WW;
    const int w    = rem - h * WW;

    // --- stage this wave's 64*81 weights into LDS via LDS-DMA (lane-linear layout) ---
    const float4* wsrc = (const float4*)(weight + (size_t)blockIdx.x * (64 * 81));
    float4* ldsb = (float4*)wlds;
    #pragma unroll
    for (int j = 0; j < 20; ++j)
        __builtin_amdgcn_global_load_lds(
            (__attribute__((address_space(1))) void*)(wsrc + j * 64 + lane),
            (__attribute__((address_space(3))) void*)(ldsb + j * 64),
            16, 0, 0);
    if (lane < 16)
        __builtin_amdgcn_global_load_lds(
            (__attribute__((address_space(1))) void*)(wsrc + 1280 + lane),
            (__attribute__((address_space(3))) void*)(ldsb + 1280),
            16, 0, 0);

    const float4* p4 = pseg + (size_t)b * PAREA;
    // center load issues before the drain -> latency hidden under the DMA
    const float4 t = p4[(h + RADIUS) * PD + (w + RADIUS)];

    __syncthreads();   // vmcnt(0) drain of the LDS-DMA

    const float* wl = &wlds[lane * 81];

    float a0 = 0.f, a1 = 0.f, a2 = 0.f, a3 = 0.f, wsum = 0.f;

    // rolling two-row register buffer: row m+1's 9 loads are in flight during row m's FMAs.
    // fully unrolled -> rows[] indices are compile-time (no scratch spill, rule #20)
    float4 rows[2][WIN];
    #pragma unroll
    for (int n = 0; n < WIN; ++n)
        rows[0][n] = p4[h * PD + w + n];

    #pragma unroll
    for (int m = 0; m < WIN; ++m) {
        const int cur = m & 1;
        const int nxt = cur ^ 1;
        if (m < WIN - 1) {
            const int base2 = (h + m + 1) * PD + w;
            #pragma unroll
            for (int n = 0; n < WIN; ++n)
                rows[nxt][n] = p4[base2 + n];
        }
        #pragma unroll
        for (int n = 0; n < WIN; ++n) {
            const float wv = wl[m * WIN + n];
            a0 = fmaf(wv, rows[cur][n].x, a0);
            a1 = fmaf(wv, rows[cur][n].y, a1);
            a2 = fmaf(wv, rows[cur][n].z, a2);
            a3 = fmaf(wv, rows[cur][n].w, a3);
            wsum += wv;
        }
    }

    float vals[8] = { a0 * t.x, a1 * t.y, a2 * t.z, a3 * t.w,
                      wsum * t.x, wsum * t.y, wsum * t.z, wsum * t.w };

    #pragma unroll
    for (int i = 0; i < 8; ++i) {
        float v = vals[i];
        v += __shfl_down(v, 32);
        v += __shfl_down(v, 16);
        v += __shfl_down(v, 8);
        v += __shfl_down(v, 4);
        v += __shfl_down(v, 2);
        v += __shfl_down(v, 1);
        vals[i] = v;
    }

    if (lane == 0) {
        const int bb     = blockIdx.x - b * BLOCKS_PER_B;
        const int bucket = bb & (NBUCKET - 1);
        float* dst = partial + (bucket * BB + b) * 8;
        #pragma unroll
        for (int i = 0; i < 8; ++i)
            atomicAdd(dst + i, vals[i]);
    }

    // --- fence-free fused finalization (isolated retry of the r7 mechanism, which passed) ---
    // Release: this wave's bucket atomics reach the coherence point before the counter bump.
    // No __threadfence -> no L2-invalidate storm (the r1 failure mode).
    asm volatile("s_waitcnt vmcnt(0)" ::: "memory");
    unsigned old = 0;
    if (lane == 0) old = atomicAdd(counter, 1u);
    old = (unsigned)__shfl((int)old, 0);

    if (old == TOTAL_BLOCKS - 1) {
        // Winner: everyone's atomics are at the coherence point.
        // Agent-scope atomic loads bypass the (possibly stale) non-coherent caches.
        float s = 0.f;
        if (lane < 32) {                         // lane = b*8 + i
            #pragma unroll 8
            for (int bucket = 0; bucket < NBUCKET; ++bucket)
                s += __hip_atomic_load(partial + bucket * 32 + lane,
                                       __ATOMIC_RELAXED, __HIP_MEMORY_SCOPE_AGENT);
        }
        const float sv = __shfl(s, lane + 4);                // matching V for A-lanes
        float term = (lane < 32 && (lane & 7) < 4) ? (s / sv) : 0.f;
        term += __shfl_down(term, 32);
        term += __shfl_down(term, 16);
        term += __shfl_down(term, 8);
        term += __shfl_down(term, 4);
        term += __shfl_down(term, 2);
        term += __shfl_down(term, 1);
        if (lane == 0)
            out[0] = (float)(BB * KK) - term;    // sum_b (K - sum_k A_k/V_k)
    }
}

extern "C" void kernel_launch(void* const* d_in, const int* in_sizes, int n_in,
                              void* d_out, int out_size, void* d_ws, size_t ws_size,
                              hipStream_t stream) {
    const float* seg    = (const float*)d_in[0];
    const float* weight = (const float*)d_in[1];
    float* out        = (float*)d_out;
    float* wsf        = (float*)d_ws;
    float* partial    = wsf;                          // 2048 floats
    unsigned* counter = (unsigned*)(wsf + 2048);
    float4* pseg      = (float4*)(wsf + 2560);        // byte offset 10240, 16B aligned

    // pre-pass: zero partials/counter + build padded seg
    {
        const int total = BB * PAREA;           // 219024
        const int grid  = (total + 255) / 256;  // 856
        hipLaunchKernelGGL(ncuts_pad, dim3(grid), dim3(256), 0, stream, seg, pseg, wsf);
    }

    // main + fence-free fused finalization (last block writes the loss)
    hipLaunchKernelGGL(ncuts_main, dim3(TOTAL_BLOCKS), dim3(64), 0, stream,
                       weight, pseg, partial, counter, out);
}

// Round 10
// 120.628 us; speedup vs baseline: 1.0984x; 1.0984x over previous
//
#include <hip/hip_runtime.h>

#define RADIUS 5
#define WIN 9
#define BB 4
#define KK 4
#define HH 224
#define WW 224
#define HW (HH * WW)
#define PD 234                 // HH + 2*RADIUS
#define PAREA (PD * PD)        // 54756
#define NBUCKET 64
#define PARTIAL_FLOATS (NBUCKET * BB * 8)   // 2048 floats = 8 KB

// ---- main tiling: block = 256 threads (4 waves) over one 56-pixel row tile ----
#define TILE_PIX 56
#define WT_PER_ROW 4                        // 224/56
#define BLOCKS_PER_B (HH * WT_PER_ROW)      // 896
#define TOTAL_BLOCKS (BB * BLOCKS_PER_B)    // 3584
#define TILE_ELEMS (TILE_PIX * 81)          // 4536 weight elements per tile
#define NSTEPS 18                           // ceil(4536/256)
#define TILE_COLS 64                        // 56 + WIN - 1 = 64 float4 per LDS row

// d_ws layout (floats):
//   [0, 2048)                      : partial buckets [bucket][b][8] (0..3 A_k, 4..7 V_k)
//   [2048, 2048 + B*PAREA*4)       : padded seg P[b][r][c][k], float4 per (r,c)

// ---------- pre-pass: zero partials + seg [B,K,H,W] -> zero-padded [B,PD,PD,K] ----------
__global__ __launch_bounds__(256) void ncuts_pad(
    const float* __restrict__ seg, float4* __restrict__ pseg, float* __restrict__ zr)
{
    const int tid = blockIdx.x * 256 + threadIdx.x;
    if (tid < PARTIAL_FLOATS) zr[tid] = 0.f;        // partial buckets
    if (tid >= BB * PAREA) return;
    const int b  = tid / PAREA;
    const int rc = tid - b * PAREA;
    const int r  = rc / PD;
    const int c  = rc - r * PD;
    const int hh = r - RADIUS;
    const int ww = c - RADIUS;
    float4 v = {0.f, 0.f, 0.f, 0.f};
    if (hh >= 0 && hh < HH && ww >= 0 && ww < WW) {
        const float* sb = seg + (size_t)b * KK * HW + hh * WW + ww;
        v.x = sb[0 * HW];
        v.y = sb[1 * HW];
        v.z = sb[2 * HW];
        v.w = sb[3 * HW];
    }
    pseg[tid] = v;
}

// ---------- main: weights global->reg (coalesced stream), pseg LDS-staged ----------
// Inverts the r2..r8 structure: the 65 MB weight stream never touches LDS (no DMA
// drain on the critical path); the small reused pseg tile (9 rows x 64 float4 =
// 9216 B) is DMA-staged once per block. Flat (pixel,slot) element loop per thread.
__global__ __launch_bounds__(256) void ncuts_main(
    const float* __restrict__ weight,
    const float4* __restrict__ pseg,
    float* __restrict__ partial)
{
    __shared__ float4 ptile[WIN * TILE_COLS];   // 9216 B -> occupancy capped by waves, not LDS

    const int tid  = threadIdx.x;          // 0..255
    const int lane = tid & 63;
    const int wid  = tid >> 6;             // 0..3
    const int blk  = blockIdx.x;
    const int b    = blk / BLOCKS_PER_B;
    const int rem  = blk - b * BLOCKS_PER_B;
    const int h    = rem >> 2;             // image row
    const int w0   = (rem & 3) * TILE_PIX; // tile start col

    // --- stage the 9x64 pseg window tile via LDS-DMA (rows split across the 4 waves) ---
    const float4* p4 = pseg + (size_t)b * PAREA;
    {
        const float4* src0 = p4 + h * PD + w0;
        #pragma unroll
        for (int rr = 0; rr < WIN; ++rr) {
            if ((rr & 3) == wid)           // wave-uniform guard
                __builtin_amdgcn_global_load_lds(
                    (__attribute__((address_space(1))) void*)(src0 + rr * PD + lane),
                    (__attribute__((address_space(3))) void*)(ptile + rr * TILE_COLS),
                    16, 0, 0);
        }
    }
    __syncthreads();   // each wave drains only its own 2-3 DMA ops; 4 waves share the stall

    // --- flat element loop: e = (local pixel q)*81 + slot o;  m=o/9, n=o%9 ---
    const float* wsrc = weight + ((size_t)b * HW + (size_t)h * WW + w0) * 81;

    unsigned e = (unsigned)tid;
    unsigned q = e / 81u;
    unsigned o = e - q * 81u;

    float a0 = 0.f, a1 = 0.f, a2 = 0.f, a3 = 0.f;
    float v0 = 0.f, v1 = 0.f, v2 = 0.f, v3 = 0.f;

    #pragma unroll
    for (int j = 0; j < NSTEPS; ++j) {
        if (e < TILE_ELEMS) {
            const float wv = wsrc[e];               // coalesced 256B/wave, straight to VGPR
            const unsigned m = o / 9u;              // magic-mul
            const unsigned n = o - m * 9u;

            const float4 sc = ptile[5 * TILE_COLS + q + 5];      // center: ~broadcast
            const float4 sv = ptile[m * TILE_COLS + q + n];      // consecutive lanes -> 2-way alias (free)

            const float t0 = wv * sc.x;
            const float t1 = wv * sc.y;
            const float t2 = wv * sc.z;
            const float t3 = wv * sc.w;
            a0 = fmaf(t0, sv.x, a0);
            a1 = fmaf(t1, sv.y, a1);
            a2 = fmaf(t2, sv.z, a2);
            a3 = fmaf(t3, sv.w, a3);
            v0 += t0; v1 += t1; v2 += t2; v3 += t3;
        }
        // advance by 256 elements: q += 3, o += 13, single wrap test
        e += 256u;
        o += 13u; q += 3u;
        if (o >= 81u) { o -= 81u; ++q; }
    }

    // --- per-wave reduction + one atomic set per wave ---
    float vals[8] = { a0, a1, a2, a3, v0, v1, v2, v3 };
    #pragma unroll
    for (int i = 0; i < 8; ++i) {
        float v = vals[i];
        v += __shfl_down(v, 32);
        v += __shfl_down(v, 16);
        v += __shfl_down(v, 8);
        v += __shfl_down(v, 4);
        v += __shfl_down(v, 2);
        v += __shfl_down(v, 1);
        vals[i] = v;
    }
    if (lane == 0) {
        const int bucket = ((blk << 2) | wid) & (NBUCKET - 1);
        float* dst = partial + (bucket * BB + b) * 8;
        #pragma unroll
        for (int i = 0; i < 8; ++i)
            atomicAdd(dst + i, vals[i]);    // fire-and-forget; no trailing wait
    }
}

// ---------- final: fold buckets, compute loss ----------
__global__ __launch_bounds__(64) void ncuts_final(
    const float* __restrict__ partial, float* __restrict__ out)
{
    __shared__ float sums[32];
    const int t = threadIdx.x;
    if (t < 32) {
        float s = 0.f;
        for (int bucket = 0; bucket < NBUCKET; ++bucket)
            s += partial[bucket * 32 + t];
        sums[t] = s;
    }
    __syncthreads();
    if (t == 0) {
        float total = 0.f;
        for (int b = 0; b < BB; ++b) {
            float assoc = 0.f;
            for (int k = 0; k < KK; ++k) {
                const float A = sums[b * 8 + k];
                const float V = sums[b * 8 + 4 + k];
                assoc += A / V;
            }
            total += (float)KK - assoc;
        }
        out[0] = total;
    }
}

extern "C" void kernel_launch(void* const* d_in, const int* in_sizes, int n_in,
                              void* d_out, int out_size, void* d_ws, size_t ws_size,
                              hipStream_t stream) {
    const float* seg    = (const float*)d_in[0];
    const float* weight = (const float*)d_in[1];
    float* out     = (float*)d_out;
    float* wsf     = (float*)d_ws;
    float* partial = wsf;                               // 2048 floats
    float4* pseg   = (float4*)(wsf + PARTIAL_FLOATS);   // byte offset 8192, 16B aligned

    // pre-pass: zero partials + build padded seg (no separate memset dispatch)
    {
        const int total = BB * PAREA;           // 219024
        const int grid  = (total + 255) / 256;  // 856
        hipLaunchKernelGGL(ncuts_pad, dim3(grid), dim3(256), 0, stream, seg, pseg, wsf);
    }

    // main: 3584 blocks x 256 threads; weights streamed to registers, pseg in LDS
    hipLaunchKernelGGL(ncuts_main, dim3(TOTAL_BLOCKS), dim3(256), 0, stream,
                       weight, pseg, partial);

    // final: fold buckets, write loss
    hipLaunchKernelGGL(ncuts_final, dim3(1), dim3(64), 0, stream, partial, out);
}

// Round 11
// 105.652 us; speedup vs baseline: 1.2541x; 1.1418x over previous
//
#include <hip/hip_runtime.h>

#define RADIUS 5
#define WIN 9
#define BB 4
#define KK 4
#define HH 224
#define WW 224
#define HW (HH * WW)
#define PD 234                 // HH + 2*RADIUS
#define PAREA (PD * PD)        // 54756
#define NBUCKET 64
#define PARTIAL_FLOATS (NBUCKET * BB * 8)   // 2048 floats = 8 KB
#define BLOCKS_PER_B (HW / 64)              // 784
#define TOTAL_BLOCKS (BB * BLOCKS_PER_B)    // 3136

// d_ws layout (floats):
//   [0, 2048)                      : partial buckets [bucket][b][8] (0..3 A_k, 4..7 V_k)
//   [2048, 2048 + B*PAREA*4)       : padded seg P[b][r][c][k], float4 per (r,c)

// ---------- pre-pass: zero partials + seg [B,K,H,W] -> zero-padded [B,PD,PD,K] ----------
__global__ __launch_bounds__(256) void ncuts_pad(
    const float* __restrict__ seg, float4* __restrict__ pseg, float* __restrict__ zr)
{
    const int tid = blockIdx.x * 256 + threadIdx.x;
    if (tid < PARTIAL_FLOATS) zr[tid] = 0.f;        // partial buckets
    if (tid >= BB * PAREA) return;
    const int b  = tid / PAREA;
    const int rc = tid - b * PAREA;
    const int r  = rc / PD;
    const int c  = rc - r * PD;
    const int hh = r - RADIUS;
    const int ww = c - RADIUS;
    float4 v = {0.f, 0.f, 0.f, 0.f};
    if (hh >= 0 && hh < HH && ww >= 0 && ww < WW) {
        const float* sb = seg + (size_t)b * KK * HW + hh * WW + ww;
        v.x = sb[0 * HW];
        v.y = sb[1 * HW];
        v.z = sb[2 * HW];
        v.w = sb[3 * HW];
    }
    pseg[tid] = v;
}

// ---------- main: one wave = 64 consecutive pixels, row-batched loads for MLP ----------
// __launch_bounds__(64,1): LDS already caps residency at 7 blocks/CU (1.75 waves/SIMD),
// so free the register allocator to keep a full window row in flight.
// Measured best (r8): 104.1 us total; main at the in-environment read-BW ceiling
// (~65 MB / ~1.9 TB/s ~= 34 us; invariant to data source per warm-replay evidence).
__global__ __launch_bounds__(64, 1) void ncuts_main(
    const float* __restrict__ weight,
    const float4* __restrict__ pseg,
    float* __restrict__ partial)
{
    __shared__ float wlds[64 * 81];   // 20736 B -> 7 blocks/CU

    const int lane = threadIdx.x;     // 0..63
    const int tid  = blockIdx.x * 64 + lane;   // pixel id
    const int b    = tid / HW;        // uniform per block (784 blocks per b)
    const int rem  = tid - b * HW;
    const int h    = rem / WW;
    const int w    = rem - h * WW;

    // --- stage this wave's 64*81 weights into LDS via LDS-DMA (lane-linear layout) ---
    const float4* wsrc = (const float4*)(weight + (size_t)blockIdx.x * (64 * 81));
    float4* ldsb = (float4*)wlds;
    #pragma unroll
    for (int j = 0; j < 20; ++j)
        __builtin_amdgcn_global_load_lds(
            (__attribute__((address_space(1))) void*)(wsrc + j * 64 + lane),
            (__attribute__((address_space(3))) void*)(ldsb + j * 64),
            16, 0, 0);
    if (lane < 16)
        __builtin_amdgcn_global_load_lds(
            (__attribute__((address_space(1))) void*)(wsrc + 1280 + lane),
            (__attribute__((address_space(3))) void*)(ldsb + 1280),
            16, 0, 0);

    const float4* p4 = pseg + (size_t)b * PAREA;
    // center load issues before the drain -> latency hidden under the DMA
    const float4 t = p4[(h + RADIUS) * PD + (w + RADIUS)];

    __syncthreads();   // vmcnt(0) drain of the LDS-DMA

    const float* wl = &wlds[lane * 81];

    float a0 = 0.f, a1 = 0.f, a2 = 0.f, a3 = 0.f, wsum = 0.f;

    #pragma unroll
    for (int m = 0; m < WIN; ++m) {
        const int base = (h + m) * PD + w;

        // batch the whole row's loads first (static indexing -> stays in VGPRs),
        // so 9+ loads are in flight before the first dependent FMA
        float4 row[WIN];
        #pragma unroll
        for (int n = 0; n < WIN; ++n)
            row[n] = p4[base + n];

        #pragma unroll
        for (int n = 0; n < WIN; ++n) {
            const float wv = wl[m * WIN + n];
            a0 = fmaf(wv, row[n].x, a0);
            a1 = fmaf(wv, row[n].y, a1);
            a2 = fmaf(wv, row[n].z, a2);
            a3 = fmaf(wv, row[n].w, a3);
            wsum += wv;
        }
    }

    float vals[8] = { a0 * t.x, a1 * t.y, a2 * t.z, a3 * t.w,
                      wsum * t.x, wsum * t.y, wsum * t.z, wsum * t.w };

    #pragma unroll
    for (int i = 0; i < 8; ++i) {
        float v = vals[i];
        v += __shfl_down(v, 32);
        v += __shfl_down(v, 16);
        v += __shfl_down(v, 8);
        v += __shfl_down(v, 4);
        v += __shfl_down(v, 2);
        v += __shfl_down(v, 1);
        vals[i] = v;
    }

    if (lane == 0) {
        const int bb     = blockIdx.x - b * BLOCKS_PER_B;
        const int bucket = bb & (NBUCKET - 1);
        float* dst = partial + (bucket * BB + b) * 8;
        #pragma unroll
        for (int i = 0; i < 8; ++i)
            atomicAdd(dst + i, vals[i]);
    }
}

// ---------- final: fold buckets, compute loss ----------
__global__ __launch_bounds__(64) void ncuts_final(
    const float* __restrict__ partial, float* __restrict__ out)
{
    __shared__ float sums[32];
    const int t = threadIdx.x;
    if (t < 32) {
        float s = 0.f;
        for (int bucket = 0; bucket < NBUCKET; ++bucket)
            s += partial[bucket * 32 + t];
        sums[t] = s;
    }
    __syncthreads();
    if (t == 0) {
        float total = 0.f;
        for (int b = 0; b < BB; ++b) {
            float assoc = 0.f;
            for (int k = 0; k < KK; ++k) {
                const float A = sums[b * 8 + k];
                const float V = sums[b * 8 + 4 + k];
                assoc += A / V;
            }
            total += (float)KK - assoc;
        }
        out[0] = total;
    }
}

extern "C" void kernel_launch(void* const* d_in, const int* in_sizes, int n_in,
                              void* d_out, int out_size, void* d_ws, size_t ws_size,
                              hipStream_t stream) {
    const float* seg    = (const float*)d_in[0];
    const float* weight = (const float*)d_in[1];
    float* out     = (float*)d_out;
    float* wsf     = (float*)d_ws;
    float* partial = wsf;                               // 2048 floats
    float4* pseg   = (float4*)(wsf + PARTIAL_FLOATS);   // byte offset 8192, 16B aligned

    // pre-pass: zero partials + build padded seg (no separate memset dispatch)
    {
        const int total = BB * PAREA;           // 219024
        const int grid  = (total + 255) / 256;  // 856
        hipLaunchKernelGGL(ncuts_pad, dim3(grid), dim3(256), 0, stream, seg, pseg, wsf);
    }

    // main
    hipLaunchKernelGGL(ncuts_main, dim3(TOTAL_BLOCKS), dim3(64), 0, stream,
                       weight, pseg, partial);

    // final: fold buckets, write loss
    hipLaunchKernelGGL(ncuts_final, dim3(1), dim3(64), 0, stream, partial, out);
}